// Round 8
// baseline (496.008 us; speedup 1.0000x reference)
//
#include <hip/hip_runtime.h>
#include <hip/hip_bf16.h>

// Problem constants
#define TT 16
#define MM 1024
#define HDIM 128
#define NHEADS 4
#define NROWS (TT*MM)          // 16384
#define MAXDEG 64

typedef __bf16 bf16x8 __attribute__((ext_vector_type(8)));
typedef float f32x4 __attribute__((ext_vector_type(4)));

__device__ __forceinline__ unsigned short f2b(float x) {   // fp32 -> bf16 RNE
    unsigned u = __float_as_uint(x);
    u += 0x7fff + ((u >> 16) & 1);
    return (unsigned short)(u >> 16);
}
__device__ __forceinline__ float bu2f(unsigned short u) {
    return __uint_as_float(((unsigned)u) << 16);
}

// ---------------- mask + neighbor-list build ----------------
__global__ __launch_bounds__(256) void k_init(const int* __restrict__ ego,
                                              float* __restrict__ mfl,
                                              int* __restrict__ cnt) {
    int idx = blockIdx.x * 256 + threadIdx.x;   // < 16384
    int t = idx >> 10, i = idx & 1023;
    int b = i >> 8, n = i & 255;
    mfl[idx] = ego[b * (TT * 256) + t * 256 + n] ? 1.f : 0.f;
    cnt[idx] = 0;
}

// 1024 blocks: t(16) x jc(64); thread covers 4 i via float4; 16 j-rows/block.
__global__ __launch_bounds__(256) void k_edges(const float* __restrict__ adj,
                                               const float* __restrict__ mfl,
                                               int* __restrict__ cnt,
                                               int* __restrict__ nbr) {
    int bid = blockIdx.x;
    int t = bid >> 6, jc = bid & 63;
    int tid = threadIdx.x;
    int i0 = tid * 4;
    int rowb = t * MM;
    float mi[4];
#pragma unroll
    for (int r = 0; r < 4; ++r) mi[r] = mfl[rowb + i0 + r];
    __shared__ float ms[16];
    if (tid < 16) ms[tid] = mfl[rowb + jc * 16 + tid];
    __syncthreads();
    const float* at = adj + (size_t)t * MM * MM;
#pragma unroll 4
    for (int jj = 0; jj < 16; ++jj) {
        int j = jc * 16 + jj;
        float4 a = *(const float4*)(at + (size_t)j * MM + i0);
        float mj = ms[jj];
#pragma unroll
        for (int r = 0; r < 4; ++r) {
            int i = i0 + r;
            bool e;
            if (j == i) e = (mi[r] != 0.f);                       // self-loop
            else e = ((&a.x)[r] != 0.f) && (mj != 0.f) && (mi[r] != 0.f);
            if (e) {
                int row = rowb + i;
                int pos = atomicAdd(&cnt[row], 1);
                if (pos < MAXDEG) nbr[(size_t)row * MAXDEG + pos] = j;
            }
        }
    }
}

// ---------------- weight prep: fp32 -> bf16 MFMA B-fragment order ----------------
__global__ __launch_bounds__(256) void k_prep(const float* __restrict__ Wqkv,
                                              const float* __restrict__ Wo,
                                              const float* __restrict__ Wff1,
                                              const float* __restrict__ Wff2,
                                              const float* __restrict__ gW,
                                              unsigned short* __restrict__ Wb) {
    int o = blockIdx.x * 256 + threadIdx.x;     // frag-unit (8 elems) index, < 163840
    const float* src; int cs;
    if (o < 122880) {
        int l = o / 24576, r = o % 24576;
        if (r < 6144) {                 // QKV
            int nt = r >> 8, rem = r & 255, ks = rem >> 6, lane = rem & 63;
            int mt = nt >> 3, cc = nt & 7;
            int k = ks * 32 + ((lane >> 4) << 3), c = cc * 16 + (lane & 15);
            src = Wqkv + ((size_t)(l * 3 + mt) * 128 + k) * 128 + c; cs = 128;
        } else if (r < 8192) {          // Wo
            int u = r - 6144, nt = u >> 8, rem = u & 255, ks = rem >> 6, lane = rem & 63;
            int k = ks * 32 + ((lane >> 4) << 3), c = nt * 16 + (lane & 15);
            src = Wo + (size_t)l * 16384 + (size_t)k * 128 + c; cs = 128;
        } else if (r < 16384) {         // FF1
            int u = r - 8192, nt = u >> 8, rem = u & 255, ks = rem >> 6, lane = rem & 63;
            int k = ks * 32 + ((lane >> 4) << 3), c = nt * 16 + (lane & 15);
            src = Wff1 + (size_t)l * 65536 + (size_t)k * 512 + c; cs = 512;
        } else {                        // FF2
            int u = r - 16384, nt = u >> 10, rem = u & 1023, ks = rem >> 6, lane = rem & 63;
            int k = ks * 32 + ((lane >> 4) << 3), c = nt * 16 + (lane & 15);
            src = Wff2 + (size_t)l * 65536 + (size_t)k * 128 + c; cs = 128;
        }
    } else {                            // GAT gW
        int u = o - 122880;
        int l = u >> 13, rr = u & 8191;
        int nt = rr >> 8, rem = rr & 255, ks = rem >> 6, lane = rem & 63;
        int k = ks * 32 + ((lane >> 4) << 3), c = nt * 16 + (lane & 15);
        src = gW + (size_t)l * 65536 + (size_t)k * 512 + c; cs = 512;
    }
    unsigned v[4];
#pragma unroll
    for (int j = 0; j < 4; ++j)
        v[j] = (unsigned)f2b(src[(2 * j) * (size_t)cs]) |
               ((unsigned)f2b(src[(2 * j + 1) * (size_t)cs]) << 16);
    *(uint4*)(Wb + (size_t)o * 8) = make_uint4(v[0], v[1], v[2], v[3]);
}

// ---------------- GAT layer 1: projection (F=2) + fused ss/sd; h -> bf16 ----------------
__global__ __launch_bounds__(128) void k_gat1(const float* __restrict__ x,
                                              const float* __restrict__ W,
                                              const float* __restrict__ asrc,
                                              const float* __restrict__ adst,
                                              unsigned short* __restrict__ h16,
                                              float* __restrict__ ss,
                                              float* __restrict__ sd) {
    int bid = blockIdx.x;
    int row = ((bid & 7) << 11) + (bid >> 3);   // XCD-locality swizzle
    int tid = threadIdx.x;
    float x0 = x[row * 2], x1 = x[row * 2 + 1];
    float s4[4], d4[4];
#pragma unroll
    for (int hh = 0; hh < 4; ++hh) {
        int o = hh * 128 + tid;
        float v = x0 * W[o] + x1 * W[512 + o];
        h16[(size_t)row * 512 + o] = f2b(v);
        s4[hh] = v * asrc[o];
        d4[hh] = v * adst[o];
    }
#pragma unroll
    for (int hh = 0; hh < 4; ++hh)
        for (int off = 32; off; off >>= 1) {
            s4[hh] += __shfl_down(s4[hh], off, 64);
            d4[hh] += __shfl_down(d4[hh], off, 64);
        }
    __shared__ float red[2][2][4];
    if ((tid & 63) == 0) {
        int w = tid >> 6;
#pragma unroll
        for (int hh = 0; hh < 4; ++hh) { red[w][0][hh] = s4[hh]; red[w][1][hh] = d4[hh]; }
    }
    __syncthreads();
    if (tid < 4) ss[row * 4 + tid] = red[0][0][tid] + red[1][0][tid];
    else if (tid < 8) sd[row * 4 + tid - 4] = red[0][1][tid - 4] + red[1][1][tid - 4];
}

// ------- GAT layers 2-6: MFMA projection, 32 rows/block, weight-amortized ----------
__global__ __launch_bounds__(256, 2) void k_gat_h(const unsigned short* __restrict__ x16,
                                                  const unsigned short* __restrict__ Wg,
                                                  const float* __restrict__ asrc,
                                                  const float* __restrict__ adst,
                                                  unsigned short* __restrict__ h16,
                                                  float* __restrict__ ss,
                                                  float* __restrict__ sd) {
    __shared__ __align__(16) unsigned short xb[32 * 136];
    int bid = blockIdx.x;
    int row0 = (((bid & 7) << 6) + (bid >> 3)) * 32;   // XCD swizzle (2 t-slices per XCD)
    int tid = threadIdx.x;
#pragma unroll
    for (int q = 0; q < 2; ++q) {
        int u = tid + q * 256;          // 0..511 frag units of 8 shorts
        int rr = u >> 4, cc = (u & 15) * 8;
        *(uint4*)(xb + rr * 136 + cc) = *(const uint4*)(x16 + (size_t)(row0 + rr) * 128 + cc);
    }
    __syncthreads();
    const int lane = tid & 63, w = tid >> 6;
    const int mrow = lane & 15, quad = lane >> 4;
    float ps[2][4] = {{0,0,0,0},{0,0,0,0}}, pd[2][4] = {{0,0,0,0},{0,0,0,0}};
#pragma unroll
    for (int ib = 0; ib < 4; ++ib) {
        bf16x8 wb[8];
#pragma unroll
        for (int u = 0; u < 2; ++u) {
            int nt = w * 8 + ib * 2 + u;
#pragma unroll
            for (int ks = 0; ks < 4; ++ks)
                wb[u * 4 + ks] = *(const bf16x8*)(Wg + (size_t)((nt * 4 + ks) * 64 + lane) * 8);
        }
#pragma unroll
        for (int rg = 0; rg < 2; ++rg) {
            bf16x8 af[4];
#pragma unroll
            for (int ks = 0; ks < 4; ++ks)
                af[ks] = *(const bf16x8*)(xb + (rg * 16 + mrow) * 136 + ks * 32 + quad * 8);
            f32x4 acc[2];
            acc[0] = (f32x4){0.f, 0.f, 0.f, 0.f};
            acc[1] = (f32x4){0.f, 0.f, 0.f, 0.f};
#pragma unroll
            for (int u = 0; u < 2; ++u)
#pragma unroll
                for (int ks = 0; ks < 4; ++ks)
                    acc[u] = __builtin_amdgcn_mfma_f32_16x16x32_bf16(af[ks], wb[u * 4 + ks], acc[u], 0, 0, 0);
#pragma unroll
            for (int u = 0; u < 2; ++u) {
                int nt = w * 8 + ib * 2 + u, col = nt * 16 + mrow;
                float as_ = asrc[col], ad_ = adst[col];
#pragma unroll
                for (int r = 0; r < 4; ++r) {
                    float v = acc[u][r];
                    h16[(size_t)(row0 + rg * 16 + quad * 4 + r) * 512 + col] = f2b(v);
                    ps[rg][r] += v * as_; pd[rg][r] += v * ad_;
                }
            }
        }
    }
#pragma unroll
    for (int off = 1; off < 16; off <<= 1)
#pragma unroll
        for (int rg = 0; rg < 2; ++rg)
#pragma unroll
            for (int r = 0; r < 4; ++r) {
                ps[rg][r] += __shfl_xor(ps[rg][r], off, 64);
                pd[rg][r] += __shfl_xor(pd[rg][r], off, 64);
            }
    if (mrow == 0) {
#pragma unroll
        for (int rg = 0; rg < 2; ++rg)
#pragma unroll
            for (int r = 0; r < 4; ++r) {
                int row = row0 + rg * 16 + quad * 4 + r;
                ss[row * 4 + w] = ps[rg][r];
                sd[row * 4 + w] = pd[rg][r];
            }
    }
}

// -------- GAT aggregation: wave-per-row, 4 rows per 256-thr block, grid 4096 --------
// R8: exact R5 body (491.9 us best); R6 unroll and R7 occupancy were both neutral.
__global__ __launch_bounds__(256, 2) void k_agg(const unsigned short* __restrict__ h16,
                                                const float* __restrict__ ss,
                                                const float* __restrict__ sd,
                                                const int* __restrict__ cnt,
                                                const int* __restrict__ nbr,
                                                const float* __restrict__ mfl,
                                                const float* __restrict__ bias,
                                                unsigned short* __restrict__ xo16) {
    __shared__ float alB[4][MAXDEG][4];
    __shared__ int   nbB[4][MAXDEG];
    __shared__ __align__(16) float partB[4][512];
    int bid = blockIdx.x;
    int row0 = (((bid & 7) << 9) + (bid >> 3)) * 4;   // XCD swizzle
    int tid = threadIdx.x;
    const int w = tid >> 6, lane = tid & 63;
    int row = row0 + w, t = row >> 10;
    bool valid = mfl[row] != 0.f;
    int c = 0;
    if (valid) { c = cnt[row]; if (c > MAXDEG) c = MAXDEG; }
    // ---- per-lane logits + in-register softmax ----
    bool act = lane < c;
    int jreg = 0;
    float lg[4];
    if (act) {
        jreg = nbr[(size_t)row * MAXDEG + lane];
        int jr = t * MM + jreg;
#pragma unroll
        for (int hh = 0; hh < 4; ++hh) {
            float v = sd[row * 4 + hh] + ss[jr * 4 + hh];
            lg[hh] = v > 0.f ? v : 0.2f * v;      // leaky_relu 0.2
        }
    } else {
#pragma unroll
        for (int hh = 0; hh < 4; ++hh) lg[hh] = -1e30f;
    }
    float mx[4];
#pragma unroll
    for (int hh = 0; hh < 4; ++hh) mx[hh] = lg[hh];
#pragma unroll
    for (int off = 32; off; off >>= 1)
#pragma unroll
        for (int hh = 0; hh < 4; ++hh) mx[hh] = fmaxf(mx[hh], __shfl_xor(mx[hh], off, 64));
    float ev[4];
#pragma unroll
    for (int hh = 0; hh < 4; ++hh) ev[hh] = act ? __expf(lg[hh] - mx[hh]) : 0.f;
    float sm[4];
#pragma unroll
    for (int hh = 0; hh < 4; ++hh) sm[hh] = ev[hh];
#pragma unroll
    for (int off = 32; off; off >>= 1)
#pragma unroll
        for (int hh = 0; hh < 4; ++hh) sm[hh] += __shfl_xor(sm[hh], off, 64);
    if (act) {
        float4 a4 = make_float4(ev[0] / sm[0], ev[1] / sm[1], ev[2] / sm[2], ev[3] / sm[3]);
        *(float4*)&alB[w][lane][0] = a4;
        nbB[w][lane] = jreg;
    }
    __syncthreads();
    // ---- gather: lane owns 8 cols (uint4 per neighbor) ----
    const int head = lane >> 4;
    float acc[8] = {0, 0, 0, 0, 0, 0, 0, 0};
    const unsigned short* hb = h16 + (size_t)t * MM * 512 + lane * 8;
    for (int n = 0; n < c; ++n) {
        int j = nbB[w][n];                 // broadcast LDS read
        float a = alB[w][n][head];
        uint4 v = *(const uint4*)(hb + (size_t)j * 512);
        acc[0] += a * bu2f((unsigned short)(v.x & 0xffff));
        acc[1] += a * bu2f((unsigned short)(v.x >> 16));
        acc[2] += a * bu2f((unsigned short)(v.y & 0xffff));
        acc[3] += a * bu2f((unsigned short)(v.y >> 16));
        acc[4] += a * bu2f((unsigned short)(v.z & 0xffff));
        acc[5] += a * bu2f((unsigned short)(v.z >> 16));
        acc[6] += a * bu2f((unsigned short)(v.w & 0xffff));
        acc[7] += a * bu2f((unsigned short)(v.w >> 16));
    }
    *(float4*)&partB[w][lane * 8]     = make_float4(acc[0], acc[1], acc[2], acc[3]);
    *(float4*)&partB[w][lane * 8 + 4] = make_float4(acc[4], acc[5], acc[6], acc[7]);
    __syncthreads();
    // ---- head-mean + bias + relu; lane handles 2 cols ----
    {
        int d0 = lane * 2;
        unsigned outp = 0;
#pragma unroll
        for (int q = 0; q < 2; ++q) {
            int d = d0 + q;
            float v = 0.f;
            if (valid) {
                v = 0.25f * (partB[w][d] + partB[w][128 + d] + partB[w][256 + d] + partB[w][384 + d])
                    + bias[d];
                v = fmaxf(v, 0.f);
            }
            outp |= ((unsigned)f2b(v)) << (16 * q);
        }
        *(unsigned*)(xo16 + (size_t)row * 128 + d0) = outp;
    }
}

// ---- LayerNorm over 32 rows x 128 (2 seqs), 256 thr, 2 rows/thread; fused bf16 conv ----
__device__ __forceinline__ void ln2x(float* xs, unsigned short* xbB,
                                     const float* s, const float* b) {
    int tid = threadIdx.x, lane = tid & 15;
#pragma unroll
    for (int half = 0; half < 2; ++half) {
        int rr = (tid >> 4) + half * 16;        // 0..31
        float* xr = xs + rr * 128;
        float sum = 0.f;
#pragma unroll
        for (int k2 = 0; k2 < 8; ++k2) sum += xr[lane + 16 * k2];
#pragma unroll
        for (int off = 8; off; off >>= 1) sum += __shfl_xor(sum, off, 16);
        float mean = sum * (1.f / 128.f);
        float vs = 0.f;
#pragma unroll
        for (int k2 = 0; k2 < 8; ++k2) { float d = xr[lane + 16 * k2] - mean; vs += d * d; }
#pragma unroll
        for (int off = 8; off; off >>= 1) vs += __shfl_xor(vs, off, 16);
        float rstd = rsqrtf(vs * (1.f / 128.f) + 1e-5f);
        unsigned short* xb = xbB + (rr >> 4) * 2176 + (rr & 15) * 136;
#pragma unroll
        for (int k2 = 0; k2 < 8; ++k2) {
            int d = lane + 16 * k2;
            float v = (xr[d] - mean) * rstd * s[d] + b[d];
            xr[d] = v;
            xb[d] = f2b(v);
        }
    }
    __syncthreads();
}

// weight batch load: 2 nt (stride-4 ks layout), 8 frags -> dst[0..7]
#define LDB(dst, base, n0, n1) do { \
    const unsigned short* p0_ = (base) + ((size_t)(n0) * 2048 + lane * 8); \
    const unsigned short* p1_ = (base) + ((size_t)(n1) * 2048 + lane * 8); \
    dst[0] = *(const bf16x8*)(p0_);        dst[1] = *(const bf16x8*)(p0_ + 512); \
    dst[2] = *(const bf16x8*)(p0_ + 1024); dst[3] = *(const bf16x8*)(p0_ + 1536); \
    dst[4] = *(const bf16x8*)(p1_);        dst[5] = *(const bf16x8*)(p1_ + 512); \
    dst[6] = *(const bf16x8*)(p1_ + 1024); dst[7] = *(const bf16x8*)(p1_ + 1536); \
} while (0)

// FF2 batch: 2 nt (stride-16 ks layout), sub-block kb, 8 frags
#define LDB2(dst, base, n0, n1, kb) do { \
    const unsigned short* p0_ = (base) + ((size_t)((n0) * 16 + (kb) * 4) * 512 + lane * 8); \
    const unsigned short* p1_ = (base) + ((size_t)((n1) * 16 + (kb) * 4) * 512 + lane * 8); \
    dst[0] = *(const bf16x8*)(p0_);        dst[1] = *(const bf16x8*)(p0_ + 512); \
    dst[2] = *(const bf16x8*)(p0_ + 1024); dst[3] = *(const bf16x8*)(p0_ + 1536); \
    dst[4] = *(const bf16x8*)(p1_);        dst[5] = *(const bf16x8*)(p1_ + 512); \
    dst[6] = *(const bf16x8*)(p1_ + 1024); dst[7] = *(const bf16x8*)(p1_ + 1536); \
} while (0)

// 2-seq x 2-nt MFMA batch into acc[2][2]
#define MF2(wv) do { \
    _Pragma("unroll") for (int s_ = 0; s_ < 2; ++s_) \
    _Pragma("unroll") for (int u_ = 0; u_ < 2; ++u_) \
    _Pragma("unroll") for (int k_ = 0; k_ < 4; ++k_) \
        acc[s_][u_] = __builtin_amdgcn_mfma_f32_16x16x32_bf16(af[s_][k_], wv[u_ * 4 + k_], acc[s_][u_], 0, 0, 0); \
} while (0)

#define ZACC do { \
    _Pragma("unroll") for (int s_ = 0; s_ < 2; ++s_) \
    _Pragma("unroll") for (int u_ = 0; u_ < 2; ++u_) \
        acc[s_][u_] = (f32x4){0.f, 0.f, 0.f, 0.f}; \
} while (0)

// ------- 5-layer transformer: 2 seqs / 256-thr block + register weight pipelining ------
// R5 base (119 us verified). R8: all weight loads are data-independent -> keep 4
// persistent 8-frag register blocks (wq/nxt/pw/pwo); each MFMA phase's first batch is
// issued at the START of the previous phase (completes under >=1000cy of compute, so
// neither the barrier drain nor the phase start pays L2 latency). Intra-phase batches
// are double-buffered. VGPR ~200 < 256 budget; occupancy is LDS-capped (2 blocks/CU)
// so the extra VGPRs are free.
__global__ __launch_bounds__(256, 2) void k_tf(const unsigned short* __restrict__ xg,
        const unsigned short* __restrict__ Wb,
        const float* __restrict__ bqkv, const float* __restrict__ bo,
        const float* __restrict__ ln1s, const float* __restrict__ ln1b,
        const float* __restrict__ ln2s, const float* __restrict__ ln2b,
        const float* __restrict__ bff1, const float* __restrict__ bff2,
        float* __restrict__ out) {
    __shared__ __align__(16) float smem[16640];             // 66560 B
    float* xs  = smem;                                      // [32][128] fp32 (2 seqs)
    float* sbB = smem + 4096;                               // [2][16tk][64] scores
    unsigned short* xbB  = (unsigned short*)(smem + 6144);  // [2][16][136] bf16 A-op
    unsigned short* qkvB = (unsigned short*)(smem + 8320);  // [2]: QKV (6528sh) | hid (8320sh)
    const int m0 = blockIdx.x * 2, tid = threadIdx.x;
    const int lane = tid & 63, w = tid >> 6;
    const int mrow = lane & 15, quad = lane >> 4;

    bf16x8 wq[8], nxt[8], pw[8], pwo[8];    // persistent weight register blocks

    // prefetch layer-0 QKV ib0 immediately (hides under PE init)
    LDB(wq, Wb, w * 6, w * 6 + 1);

    // load + sinusoidal PE (both seqs; xs layout [sid][t][d] contiguous)
    for (int idx = tid; idx < 4096; idx += 256) {
        int sq = idx >> 11, t = (idx >> 7) & 15, d = idx & 127, jj = d >> 1;
        float arg = (float)t * expf(-(float)(2 * jj) * (9.210340371976184f / 128.f));
        float pe = (d & 1) ? cosf(arg) : sinf(arg);
        xs[idx] = bu2f(xg[(size_t)t * (MM * HDIM) + (size_t)(m0 + sq) * HDIM + d]) + pe;
    }
    __syncthreads();
    // initial xs -> xbB (LN epilogues keep it fresh afterwards)
#pragma unroll
    for (int half = 0; half < 2; ++half) {
        int u = tid + half * 256;                // 512 units of 8 elems
        int rr = u >> 4, cc = (u & 15) * 8;
        const float* xp = xs + rr * 128 + cc;
        unsigned v[4];
#pragma unroll
        for (int j = 0; j < 4; ++j)
            v[j] = (unsigned)f2b(xp[2 * j]) | ((unsigned)f2b(xp[2 * j + 1]) << 16);
        *(uint4*)(xbB + (rr >> 4) * 2176 + (rr & 15) * 136 + cc) = make_uint4(v[0], v[1], v[2], v[3]);
    }
    __syncthreads();

    for (int l = 0; l < 5; ++l) {
        const unsigned short* Wl = Wb + (size_t)l * 196608;
        // ---- QKV: ib0 pre-resident in wq; ib1/ib2 double-buffered; Wo prefetch issued ----
        {
            bf16x8 af[2][4];
#pragma unroll
            for (int sid = 0; sid < 2; ++sid)
#pragma unroll
                for (int ks = 0; ks < 4; ++ks)
                    af[sid][ks] = *(const bf16x8*)(xbB + sid * 2176 + mrow * 136 + ks * 32 + quad * 8);
            LDB(nxt, Wl, w * 6 + 2, w * 6 + 3);          // ib1
            LDB(pwo, Wl + 49152, w * 2, w * 2 + 1);      // Wo prefetch (completes under QKV)
            f32x4 acc[2][2];
#pragma unroll
            for (int ib = 0; ib < 3; ++ib) {
                ZACC;
                if (ib == 0)      { MF2(wq); LDB(wq, Wl, w * 6 + 4, w * 6 + 5); }  // issue ib2
                else if (ib == 1) { MF2(nxt); }
                else              { MF2(wq); }
#pragma unroll
                for (int sid = 0; sid < 2; ++sid)
#pragma unroll
                    for (int u = 0; u < 2; ++u) {
                        int nt = w * 6 + ib * 2 + u, mt = nt >> 3, cc = nt & 7;
                        int col = cc * 16 + mrow;
                        float bb = bqkv[l * 384 + mt * 128 + col];
                        unsigned short* dst = qkvB + sid * 6528 + mt * 2176;   // Q/K/V of sid
#pragma unroll
                        for (int r = 0; r < 4; ++r)
                            dst[(quad * 4 + r) * 136 + col] = f2b(acc[sid][u][r] + bb);
                    }
            }
        }
        __syncthreads();
        // ---- scores (fp32 VALU, bf16 Q/K): thread = (hh, tq, tk0..tk0+3) x 2 seqs ----
        {
            int hh = tid >> 6, tq = (tid >> 2) & 15, tk0 = (tid & 3) * 4;
#pragma unroll
            for (int sid = 0; sid < 2; ++sid) {
                const unsigned short* qp = qkvB + sid * 6528 + tq * 136 + hh * 32;
                const unsigned short* kb = qkvB + sid * 6528 + 2176;
                float a[4] = {0.f, 0.f, 0.f, 0.f};
#pragma unroll
                for (int d4 = 0; d4 < 4; ++d4) {
                    uint4 qv = *(const uint4*)(qp + d4 * 8);
                    float qf[8];
                    qf[0] = bu2f((unsigned short)(qv.x & 0xffff)); qf[1] = bu2f((unsigned short)(qv.x >> 16));
                    qf[2] = bu2f((unsigned short)(qv.y & 0xffff)); qf[3] = bu2f((unsigned short)(qv.y >> 16));
                    qf[4] = bu2f((unsigned short)(qv.z & 0xffff)); qf[5] = bu2f((unsigned short)(qv.z >> 16));
                    qf[6] = bu2f((unsigned short)(qv.w & 0xffff)); qf[7] = bu2f((unsigned short)(qv.w >> 16));
#pragma unroll
                    for (int j = 0; j < 4; ++j) {
                        uint4 kv = *(const uint4*)(kb + (tk0 + j) * 136 + hh * 32 + d4 * 8);
                        a[j] += qf[0] * bu2f((unsigned short)(kv.x & 0xffff));
                        a[j] += qf[1] * bu2f((unsigned short)(kv.x >> 16));
                        a[j] += qf[2] * bu2f((unsigned short)(kv.y & 0xffff));
                        a[j] += qf[3] * bu2f((unsigned short)(kv.y >> 16));
                        a[j] += qf[4] * bu2f((unsigned short)(kv.z & 0xffff));
                        a[j] += qf[5] * bu2f((unsigned short)(kv.z >> 16));
                        a[j] += qf[6] * bu2f((unsigned short)(kv.w & 0xffff));
                        a[j] += qf[7] * bu2f((unsigned short)(kv.w >> 16));
                    }
                }
#pragma unroll
                for (int j = 0; j < 4; ++j)
                    sbB[sid * 1024 + (tk0 + j) * 64 + hh * 16 + tq] = a[j] * 0.17677669529663687f;
            }
        }
        __syncthreads();
        if (tid < 128) {   // softmax per (seq, hh, tq) column
            float* sbp = sbB + (tid >> 6) * 1024;
            int cc = tid & 63;
            float mx = -1e30f;
#pragma unroll
            for (int u = 0; u < 16; ++u) mx = fmaxf(mx, sbp[u * 64 + cc]);
            float s = 0.f;
#pragma unroll
            for (int u = 0; u < 16; ++u) { float e = __expf(sbp[u * 64 + cc] - mx); sbp[u * 64 + cc] = e; s += e; }
            float inv = 1.f / s;
#pragma unroll
            for (int u = 0; u < 16; ++u) sbp[u * 64 + cc] *= inv;
        }
        __syncthreads();
        // ---- O = P @ V (fp32, bf16 V) -> xbB, both seqs ----
        {
            int o = tid & 127, r0p = (tid >> 7) * 8, hh = o >> 5;
#pragma unroll
            for (int sid = 0; sid < 2; ++sid) {
                const unsigned short* vb = qkvB + sid * 6528 + 4352;
                const float* sb = sbB + sid * 1024;
                float accp[8] = {0, 0, 0, 0, 0, 0, 0, 0};
                for (int u = 0; u < 16; ++u) {
                    float vv = bu2f(vb[u * 136 + o]);
                    const float* pp = sb + u * 64 + hh * 16 + r0p;
#pragma unroll
                    for (int r = 0; r < 8; ++r) accp[r] += pp[r] * vv;
                }
#pragma unroll
                for (int r = 0; r < 8; ++r)
                    xbB[sid * 2176 + (r0p + r) * 136 + o] = f2b(accp[r]);
            }
        }
        __syncthreads();
        // ---- Wo: weights pre-resident in pwo; FF1 ib0 prefetch issued ----
        {
            bf16x8 af[2][4];
#pragma unroll
            for (int sid = 0; sid < 2; ++sid)
#pragma unroll
                for (int ks = 0; ks < 4; ++ks)
                    af[sid][ks] = *(const bf16x8*)(xbB + sid * 2176 + mrow * 136 + ks * 32 + quad * 8);
            LDB(pw, Wl + 65536, w * 8, w * 8 + 1);       // FF1 ib0 prefetch
            f32x4 acc[2][2];
            ZACC;
            MF2(pwo);
#pragma unroll
            for (int sid = 0; sid < 2; ++sid)
#pragma unroll
                for (int u = 0; u < 2; ++u) {
                    int col = (w * 2 + u) * 16 + mrow;
                    float bb = bo[l * 128 + col];
#pragma unroll
                    for (int r = 0; r < 4; ++r)
                        xs[sid * 2048 + (quad * 4 + r) * 128 + col] += acc[sid][u][r] + bb;
                }
        }
        __syncthreads();
        ln2x(xs, xbB, ln1s + l * 128, ln1b + l * 128);     // also refreshes xbB
        // ---- FF1: ib0 pre-resident in pw; ib1-3 double-buffered; FF2 kb0 prefetch ----
        {
            bf16x8 af[2][4];
#pragma unroll
            for (int sid = 0; sid < 2; ++sid)
#pragma unroll
                for (int ks = 0; ks < 4; ++ks)
                    af[sid][ks] = *(const bf16x8*)(xbB + sid * 2176 + mrow * 136 + ks * 32 + quad * 8);
            const unsigned short* Ws = Wl + 65536;
            LDB(nxt, Ws, w * 8 + 2, w * 8 + 3);                    // ib1
            LDB2(pwo, Wl + 131072, w * 2, w * 2 + 1, 0);           // FF2 kb0 prefetch
            f32x4 acc[2][2];
#pragma unroll
            for (int ib = 0; ib < 4; ++ib) {
                ZACC;
                if (ib == 0)      { MF2(pw);  LDB(pw,  Ws, w * 8 + 4, w * 8 + 5); }  // ib2
                else if (ib == 1) { MF2(nxt); LDB(nxt, Ws, w * 8 + 6, w * 8 + 7); }  // ib3
                else if (ib == 2) { MF2(pw); }
                else              { MF2(nxt); }
#pragma unroll
                for (int sid = 0; sid < 2; ++sid)
#pragma unroll
                    for (int u = 0; u < 2; ++u) {
                        int col = (w * 8 + ib * 2 + u) * 16 + mrow;
                        float bb = bff1[l * 512 + col];
                        unsigned short* hid16 = qkvB + sid * 8320;
#pragma unroll
                        for (int r = 0; r < 4; ++r) {
                            float v = fmaxf(acc[sid][u][r] + bb, 0.f);
                            hid16[(quad * 4 + r) * 520 + col] = f2b(v);
                        }
                    }
            }
        }
        __syncthreads();
        // ---- FF2: kb0 pre-resident in pwo; kb1-3 double-buffered; next QKV prefetch ----
        {
            f32x4 a[2][2];
#pragma unroll
            for (int sid = 0; sid < 2; ++sid)
#pragma unroll
                for (int u = 0; u < 2; ++u) a[sid][u] = (f32x4){0.f, 0.f, 0.f, 0.f};
            const unsigned short* Ws = Wl + 131072;
            int nt0 = w * 2, nt1 = w * 2 + 1;
            LDB2(pw, Ws, nt0, nt1, 1);                               // kb1
            if (l < 4) LDB(wq, Wl + 196608, w * 6, w * 6 + 1);       // next-layer QKV ib0
#pragma unroll
            for (int kb = 0; kb < 4; ++kb) {
#pragma unroll
                for (int sid = 0; sid < 2; ++sid) {
                    const unsigned short* hid16 = qkvB + sid * 8320;
#pragma unroll
                    for (int kk = 0; kk < 4; ++kk) {
                        int ks = kb * 4 + kk;
                        bf16x8 afb = *(const bf16x8*)(hid16 + mrow * 520 + ks * 32 + quad * 8);
                        if (kb == 0 || kb == 2) {
                            a[sid][0] = __builtin_amdgcn_mfma_f32_16x16x32_bf16(afb, pwo[kk],     a[sid][0], 0, 0, 0);
                            a[sid][1] = __builtin_amdgcn_mfma_f32_16x16x32_bf16(afb, pwo[4 + kk], a[sid][1], 0, 0, 0);
                        } else {
                            a[sid][0] = __builtin_amdgcn_mfma_f32_16x16x32_bf16(afb, pw[kk],      a[sid][0], 0, 0, 0);
                            a[sid][1] = __builtin_amdgcn_mfma_f32_16x16x32_bf16(afb, pw[4 + kk],  a[sid][1], 0, 0, 0);
                        }
                    }
                }
                if (kb == 0)      { LDB2(pwo, Ws, nt0, nt1, 2); }    // kb2 into pwo
                else if (kb == 1) { LDB2(pw,  Ws, nt0, nt1, 3); }    // kb3 into pw
            }
            int col0 = nt0 * 16 + mrow, col1 = nt1 * 16 + mrow;
            float bb0 = bff2[l * 128 + col0], bb1 = bff2[l * 128 + col1];
#pragma unroll
            for (int sid = 0; sid < 2; ++sid)
#pragma unroll
                for (int r = 0; r < 4; ++r) {
                    xs[sid * 2048 + (quad * 4 + r) * 128 + col0] += a[sid][0][r] + bb0;
                    xs[sid * 2048 + (quad * 4 + r) * 128 + col1] += a[sid][1][r] + bb1;
                }
        }
        __syncthreads();
        ln2x(xs, xbB, ln2s + l * 128, ln2b + l * 128);     // xbB ready for next layer
    }
    for (int idx = tid; idx < 4096; idx += 256)
        out[(size_t)m0 * 2048 + idx] = xs[idx];
}

extern "C" void kernel_launch(void* const* d_in, const int* in_sizes, int n_in,
                              void* d_out, int out_size, void* d_ws, size_t ws_size,
                              hipStream_t stream) {
    (void)in_sizes; (void)n_in; (void)out_size; (void)ws_size;
    const int*   ego  = (const int*)d_in[0];
    const float* pos  = (const float*)d_in[1];
    const float* adj  = (const float*)d_in[2];
    const float* g1W  = (const float*)d_in[3];
    const float* g1as = (const float*)d_in[4];
    const float* g1ad = (const float*)d_in[5];
    const float* g1b  = (const float*)d_in[6];
    const float* gW   = (const float*)d_in[7];
    const float* gas  = (const float*)d_in[8];
    const float* gad  = (const float*)d_in[9];
    const float* gb   = (const float*)d_in[10];
    const float* Wqkv = (const float*)d_in[11];
    const float* bqkv = (const float*)d_in[12];
    const float* Wo   = (const float*)d_in[13];
    const float* bo   = (const float*)d_in[14];
    const float* l1s  = (const float*)d_in[15];
    const float* l1b  = (const float*)d_in[16];
    const float* l2s  = (const float*)d_in[17];
    const float* l2b  = (const float*)d_in[18];
    const float* Wff1 = (const float*)d_in[19];
    const float* bff1 = (const float*)d_in[20];
    const float* Wff2 = (const float*)d_in[21];
    const float* bff2 = (const float*)d_in[22];

    unsigned short* x0  = (unsigned short*)d_ws;       // 2,097,152 sh (4 MB)
    unsigned short* x1  = x0 + 2097152;                // 4 MB
    unsigned short* h16 = x1 + 2097152;                // 8,388,608 sh (16 MB)
    float* ssb = (float*)(h16 + 8388608);              // 65,536 f
    float* sdb = ssb + 65536;                          // 65,536 f
    float* mfl = sdb + 65536;                          // 16,384 f
    int*   cnt = (int*)(mfl + 16384);                  // 16,384 i
    int*   nbr = cnt + 16384;                          // 1,048,576 i
    unsigned short* Wb16 = (unsigned short*)(nbr + 1048576);  // 1,310,720 sh (~2.6 MB)
    unsigned short* Wg16 = Wb16 + 983040;              // GAT weight frags

    k_prep<<<640, 256, 0, stream>>>(Wqkv, Wo, Wff1, Wff2, gW, Wb16);
    k_init<<<64, 256, 0, stream>>>(ego, mfl, cnt);
    k_edges<<<1024, 256, 0, stream>>>(adj, mfl, cnt, nbr);

    // GAT layer 1 (F=2), projection + ss/sd fused
    k_gat1<<<NROWS, 128, 0, stream>>>(pos, g1W, g1as, g1ad, h16, ssb, sdb);
    k_agg<<<4096, 256, 0, stream>>>(h16, ssb, sdb, cnt, nbr, mfl, g1b, x0);

    unsigned short* xin = x0; unsigned short* xout = x1;
    for (int L = 0; L < 5; ++L) {
        k_gat_h<<<512, 256, 0, stream>>>(xin, Wg16 + (size_t)L * 65536,
                                         gas + L * 512, gad + L * 512, h16, ssb, sdb);
        k_agg<<<4096, 256, 0, stream>>>(h16, ssb, sdb, cnt, nbr, mfl, gb + L * 128, xout);
        unsigned short* tmp = xin; xin = xout; xout = tmp;
    }

    k_tf<<<512, 256, 0, stream>>>(xin, Wb16, bqkv, bo, l1s, l1b, l2s, l2b,
                                  bff1, bff2, (float*)d_out);
}

// Round 9
// 488.416 us; speedup vs baseline: 1.0155x; 1.0155x over previous
//
#include <hip/hip_runtime.h>
#include <hip/hip_bf16.h>

// Problem constants
#define TT 16
#define MM 1024
#define HDIM 128
#define NHEADS 4
#define NROWS (TT*MM)          // 16384
#define MAXDEG 64

typedef __bf16 bf16x8 __attribute__((ext_vector_type(8)));
typedef float f32x4 __attribute__((ext_vector_type(4)));

__device__ __forceinline__ unsigned short f2b(float x) {   // fp32 -> bf16 RNE
    unsigned u = __float_as_uint(x);
    u += 0x7fff + ((u >> 16) & 1);
    return (unsigned short)(u >> 16);
}
__device__ __forceinline__ float bu2f(unsigned short u) {
    return __uint_as_float(((unsigned)u) << 16);
}

// ---------------- mask + neighbor-list build ----------------
__global__ __launch_bounds__(256) void k_init(const int* __restrict__ ego,
                                              float* __restrict__ mfl,
                                              int* __restrict__ cnt) {
    int idx = blockIdx.x * 256 + threadIdx.x;   // < 16384
    int t = idx >> 10, i = idx & 1023;
    int b = i >> 8, n = i & 255;
    mfl[idx] = ego[b * (TT * 256) + t * 256 + n] ? 1.f : 0.f;
    cnt[idx] = 0;
}

// 1024 blocks: t(16) x jc(64); thread covers 4 i via float4; 16 j-rows/block.
__global__ __launch_bounds__(256) void k_edges(const float* __restrict__ adj,
                                               const float* __restrict__ mfl,
                                               int* __restrict__ cnt,
                                               int* __restrict__ nbr) {
    int bid = blockIdx.x;
    int t = bid >> 6, jc = bid & 63;
    int tid = threadIdx.x;
    int i0 = tid * 4;
    int rowb = t * MM;
    float mi[4];
#pragma unroll
    for (int r = 0; r < 4; ++r) mi[r] = mfl[rowb + i0 + r];
    __shared__ float ms[16];
    if (tid < 16) ms[tid] = mfl[rowb + jc * 16 + tid];
    __syncthreads();
    const float* at = adj + (size_t)t * MM * MM;
#pragma unroll 4
    for (int jj = 0; jj < 16; ++jj) {
        int j = jc * 16 + jj;
        float4 a = *(const float4*)(at + (size_t)j * MM + i0);
        float mj = ms[jj];
#pragma unroll
        for (int r = 0; r < 4; ++r) {
            int i = i0 + r;
            bool e;
            if (j == i) e = (mi[r] != 0.f);                       // self-loop
            else e = ((&a.x)[r] != 0.f) && (mj != 0.f) && (mi[r] != 0.f);
            if (e) {
                int row = rowb + i;
                int pos = atomicAdd(&cnt[row], 1);
                if (pos < MAXDEG) nbr[(size_t)row * MAXDEG + pos] = j;
            }
        }
    }
}

// ---------------- weight prep: fp32 -> bf16 MFMA B-fragment order ----------------
__global__ __launch_bounds__(256) void k_prep(const float* __restrict__ Wqkv,
                                              const float* __restrict__ Wo,
                                              const float* __restrict__ Wff1,
                                              const float* __restrict__ Wff2,
                                              const float* __restrict__ gW,
                                              unsigned short* __restrict__ Wb) {
    int o = blockIdx.x * 256 + threadIdx.x;     // frag-unit (8 elems) index, < 163840
    const float* src; int cs;
    if (o < 122880) {
        int l = o / 24576, r = o % 24576;
        if (r < 6144) {                 // QKV
            int nt = r >> 8, rem = r & 255, ks = rem >> 6, lane = rem & 63;
            int mt = nt >> 3, cc = nt & 7;
            int k = ks * 32 + ((lane >> 4) << 3), c = cc * 16 + (lane & 15);
            src = Wqkv + ((size_t)(l * 3 + mt) * 128 + k) * 128 + c; cs = 128;
        } else if (r < 8192) {          // Wo
            int u = r - 6144, nt = u >> 8, rem = u & 255, ks = rem >> 6, lane = rem & 63;
            int k = ks * 32 + ((lane >> 4) << 3), c = nt * 16 + (lane & 15);
            src = Wo + (size_t)l * 16384 + (size_t)k * 128 + c; cs = 128;
        } else if (r < 16384) {         // FF1
            int u = r - 8192, nt = u >> 8, rem = u & 255, ks = rem >> 6, lane = rem & 63;
            int k = ks * 32 + ((lane >> 4) << 3), c = nt * 16 + (lane & 15);
            src = Wff1 + (size_t)l * 65536 + (size_t)k * 512 + c; cs = 512;
        } else {                        // FF2
            int u = r - 16384, nt = u >> 10, rem = u & 1023, ks = rem >> 6, lane = rem & 63;
            int k = ks * 32 + ((lane >> 4) << 3), c = nt * 16 + (lane & 15);
            src = Wff2 + (size_t)l * 65536 + (size_t)k * 128 + c; cs = 128;
        }
    } else {                            // GAT gW
        int u = o - 122880;
        int l = u >> 13, rr = u & 8191;
        int nt = rr >> 8, rem = rr & 255, ks = rem >> 6, lane = rem & 63;
        int k = ks * 32 + ((lane >> 4) << 3), c = nt * 16 + (lane & 15);
        src = gW + (size_t)l * 65536 + (size_t)k * 512 + c; cs = 512;
    }
    unsigned v[4];
#pragma unroll
    for (int j = 0; j < 4; ++j)
        v[j] = (unsigned)f2b(src[(2 * j) * (size_t)cs]) |
               ((unsigned)f2b(src[(2 * j + 1) * (size_t)cs]) << 16);
    *(uint4*)(Wb + (size_t)o * 8) = make_uint4(v[0], v[1], v[2], v[3]);
}

// ---------------- GAT layer 1: projection (F=2) + fused ss/sd; h -> bf16 ----------------
__global__ __launch_bounds__(128) void k_gat1(const float* __restrict__ x,
                                              const float* __restrict__ W,
                                              const float* __restrict__ asrc,
                                              const float* __restrict__ adst,
                                              unsigned short* __restrict__ h16,
                                              float* __restrict__ ss,
                                              float* __restrict__ sd) {
    int bid = blockIdx.x;
    int row = ((bid & 7) << 11) + (bid >> 3);   // XCD-locality swizzle
    int tid = threadIdx.x;
    float x0 = x[row * 2], x1 = x[row * 2 + 1];
    float s4[4], d4[4];
#pragma unroll
    for (int hh = 0; hh < 4; ++hh) {
        int o = hh * 128 + tid;
        float v = x0 * W[o] + x1 * W[512 + o];
        h16[(size_t)row * 512 + o] = f2b(v);
        s4[hh] = v * asrc[o];
        d4[hh] = v * adst[o];
    }
#pragma unroll
    for (int hh = 0; hh < 4; ++hh)
        for (int off = 32; off; off >>= 1) {
            s4[hh] += __shfl_down(s4[hh], off, 64);
            d4[hh] += __shfl_down(d4[hh], off, 64);
        }
    __shared__ float red[2][2][4];
    if ((tid & 63) == 0) {
        int w = tid >> 6;
#pragma unroll
        for (int hh = 0; hh < 4; ++hh) { red[w][0][hh] = s4[hh]; red[w][1][hh] = d4[hh]; }
    }
    __syncthreads();
    if (tid < 4) ss[row * 4 + tid] = red[0][0][tid] + red[1][0][tid];
    else if (tid < 8) sd[row * 4 + tid - 4] = red[0][1][tid - 4] + red[1][1][tid - 4];
}

// ------- GAT layers 2-6: MFMA projection, 32 rows/block, weight-amortized ----------
__global__ __launch_bounds__(256, 2) void k_gat_h(const unsigned short* __restrict__ x16,
                                                  const unsigned short* __restrict__ Wg,
                                                  const float* __restrict__ asrc,
                                                  const float* __restrict__ adst,
                                                  unsigned short* __restrict__ h16,
                                                  float* __restrict__ ss,
                                                  float* __restrict__ sd) {
    __shared__ __align__(16) unsigned short xb[32 * 136];
    int bid = blockIdx.x;
    int row0 = (((bid & 7) << 6) + (bid >> 3)) * 32;   // XCD swizzle (2 t-slices per XCD)
    int tid = threadIdx.x;
#pragma unroll
    for (int q = 0; q < 2; ++q) {
        int u = tid + q * 256;          // 0..511 frag units of 8 shorts
        int rr = u >> 4, cc = (u & 15) * 8;
        *(uint4*)(xb + rr * 136 + cc) = *(const uint4*)(x16 + (size_t)(row0 + rr) * 128 + cc);
    }
    __syncthreads();
    const int lane = tid & 63, w = tid >> 6;
    const int mrow = lane & 15, quad = lane >> 4;
    float ps[2][4] = {{0,0,0,0},{0,0,0,0}}, pd[2][4] = {{0,0,0,0},{0,0,0,0}};
#pragma unroll
    for (int ib = 0; ib < 4; ++ib) {
        bf16x8 wb[8];
#pragma unroll
        for (int u = 0; u < 2; ++u) {
            int nt = w * 8 + ib * 2 + u;
#pragma unroll
            for (int ks = 0; ks < 4; ++ks)
                wb[u * 4 + ks] = *(const bf16x8*)(Wg + (size_t)((nt * 4 + ks) * 64 + lane) * 8);
        }
#pragma unroll
        for (int rg = 0; rg < 2; ++rg) {
            bf16x8 af[4];
#pragma unroll
            for (int ks = 0; ks < 4; ++ks)
                af[ks] = *(const bf16x8*)(xb + (rg * 16 + mrow) * 136 + ks * 32 + quad * 8);
            f32x4 acc[2];
            acc[0] = (f32x4){0.f, 0.f, 0.f, 0.f};
            acc[1] = (f32x4){0.f, 0.f, 0.f, 0.f};
#pragma unroll
            for (int u = 0; u < 2; ++u)
#pragma unroll
                for (int ks = 0; ks < 4; ++ks)
                    acc[u] = __builtin_amdgcn_mfma_f32_16x16x32_bf16(af[ks], wb[u * 4 + ks], acc[u], 0, 0, 0);
#pragma unroll
            for (int u = 0; u < 2; ++u) {
                int nt = w * 8 + ib * 2 + u, col = nt * 16 + mrow;
                float as_ = asrc[col], ad_ = adst[col];
#pragma unroll
                for (int r = 0; r < 4; ++r) {
                    float v = acc[u][r];
                    h16[(size_t)(row0 + rg * 16 + quad * 4 + r) * 512 + col] = f2b(v);
                    ps[rg][r] += v * as_; pd[rg][r] += v * ad_;
                }
            }
        }
    }
#pragma unroll
    for (int off = 1; off < 16; off <<= 1)
#pragma unroll
        for (int rg = 0; rg < 2; ++rg)
#pragma unroll
            for (int r = 0; r < 4; ++r) {
                ps[rg][r] += __shfl_xor(ps[rg][r], off, 64);
                pd[rg][r] += __shfl_xor(pd[rg][r], off, 64);
            }
    if (mrow == 0) {
#pragma unroll
        for (int rg = 0; rg < 2; ++rg)
#pragma unroll
            for (int r = 0; r < 4; ++r) {
                int row = row0 + rg * 16 + quad * 4 + r;
                ss[row * 4 + w] = ps[rg][r];
                sd[row * 4 + w] = pd[rg][r];
            }
    }
}

// -------- GAT aggregation: wave-per-row, 4 rows per 256-thr block, grid 4096 --------
// Exact R5 body (491.9 us best); R6 unroll and R7 occupancy were both neutral.
__global__ __launch_bounds__(256, 2) void k_agg(const unsigned short* __restrict__ h16,
                                                const float* __restrict__ ss,
                                                const float* __restrict__ sd,
                                                const int* __restrict__ cnt,
                                                const int* __restrict__ nbr,
                                                const float* __restrict__ mfl,
                                                const float* __restrict__ bias,
                                                unsigned short* __restrict__ xo16) {
    __shared__ float alB[4][MAXDEG][4];
    __shared__ int   nbB[4][MAXDEG];
    __shared__ __align__(16) float partB[4][512];
    int bid = blockIdx.x;
    int row0 = (((bid & 7) << 9) + (bid >> 3)) * 4;   // XCD swizzle
    int tid = threadIdx.x;
    const int w = tid >> 6, lane = tid & 63;
    int row = row0 + w, t = row >> 10;
    bool valid = mfl[row] != 0.f;
    int c = 0;
    if (valid) { c = cnt[row]; if (c > MAXDEG) c = MAXDEG; }
    // ---- per-lane logits + in-register softmax ----
    bool act = lane < c;
    int jreg = 0;
    float lg[4];
    if (act) {
        jreg = nbr[(size_t)row * MAXDEG + lane];
        int jr = t * MM + jreg;
#pragma unroll
        for (int hh = 0; hh < 4; ++hh) {
            float v = sd[row * 4 + hh] + ss[jr * 4 + hh];
            lg[hh] = v > 0.f ? v : 0.2f * v;      // leaky_relu 0.2
        }
    } else {
#pragma unroll
        for (int hh = 0; hh < 4; ++hh) lg[hh] = -1e30f;
    }
    float mx[4];
#pragma unroll
    for (int hh = 0; hh < 4; ++hh) mx[hh] = lg[hh];
#pragma unroll
    for (int off = 32; off; off >>= 1)
#pragma unroll
        for (int hh = 0; hh < 4; ++hh) mx[hh] = fmaxf(mx[hh], __shfl_xor(mx[hh], off, 64));
    float ev[4];
#pragma unroll
    for (int hh = 0; hh < 4; ++hh) ev[hh] = act ? __expf(lg[hh] - mx[hh]) : 0.f;
    float sm[4];
#pragma unroll
    for (int hh = 0; hh < 4; ++hh) sm[hh] = ev[hh];
#pragma unroll
    for (int off = 32; off; off >>= 1)
#pragma unroll
        for (int hh = 0; hh < 4; ++hh) sm[hh] += __shfl_xor(sm[hh], off, 64);
    if (act) {
        float4 a4 = make_float4(ev[0] / sm[0], ev[1] / sm[1], ev[2] / sm[2], ev[3] / sm[3]);
        *(float4*)&alB[w][lane][0] = a4;
        nbB[w][lane] = jreg;
    }
    __syncthreads();
    // ---- gather: lane owns 8 cols (uint4 per neighbor) ----
    const int head = lane >> 4;
    float acc[8] = {0, 0, 0, 0, 0, 0, 0, 0};
    const unsigned short* hb = h16 + (size_t)t * MM * 512 + lane * 8;
    for (int n = 0; n < c; ++n) {
        int j = nbB[w][n];                 // broadcast LDS read
        float a = alB[w][n][head];
        uint4 v = *(const uint4*)(hb + (size_t)j * 512);
        acc[0] += a * bu2f((unsigned short)(v.x & 0xffff));
        acc[1] += a * bu2f((unsigned short)(v.x >> 16));
        acc[2] += a * bu2f((unsigned short)(v.y & 0xffff));
        acc[3] += a * bu2f((unsigned short)(v.y >> 16));
        acc[4] += a * bu2f((unsigned short)(v.z & 0xffff));
        acc[5] += a * bu2f((unsigned short)(v.z >> 16));
        acc[6] += a * bu2f((unsigned short)(v.w & 0xffff));
        acc[7] += a * bu2f((unsigned short)(v.w >> 16));
    }
    *(float4*)&partB[w][lane * 8]     = make_float4(acc[0], acc[1], acc[2], acc[3]);
    *(float4*)&partB[w][lane * 8 + 4] = make_float4(acc[4], acc[5], acc[6], acc[7]);
    __syncthreads();
    // ---- head-mean + bias + relu; lane handles 2 cols ----
    {
        int d0 = lane * 2;
        unsigned outp = 0;
#pragma unroll
        for (int q = 0; q < 2; ++q) {
            int d = d0 + q;
            float v = 0.f;
            if (valid) {
                v = 0.25f * (partB[w][d] + partB[w][128 + d] + partB[w][256 + d] + partB[w][384 + d])
                    + bias[d];
                v = fmaxf(v, 0.f);
            }
            outp |= ((unsigned)f2b(v)) << (16 * q);
        }
        *(unsigned*)(xo16 + (size_t)row * 128 + d0) = outp;
    }
}

// ---- LayerNorm over 32 rows x 128 (2 seqs), 256 thr, 2 rows/thread; fused bf16 conv ----
__device__ __forceinline__ void ln2x(float* xs, unsigned short* xbB,
                                     const float* s, const float* b) {
    int tid = threadIdx.x, lane = tid & 15;
#pragma unroll
    for (int half = 0; half < 2; ++half) {
        int rr = (tid >> 4) + half * 16;        // 0..31
        float* xr = xs + rr * 128;
        float sum = 0.f;
#pragma unroll
        for (int k2 = 0; k2 < 8; ++k2) sum += xr[lane + 16 * k2];
#pragma unroll
        for (int off = 8; off; off >>= 1) sum += __shfl_xor(sum, off, 16);
        float mean = sum * (1.f / 128.f);
        float vs = 0.f;
#pragma unroll
        for (int k2 = 0; k2 < 8; ++k2) { float d = xr[lane + 16 * k2] - mean; vs += d * d; }
#pragma unroll
        for (int off = 8; off; off >>= 1) vs += __shfl_xor(vs, off, 16);
        float rstd = rsqrtf(vs * (1.f / 128.f) + 1e-5f);
        unsigned short* xb = xbB + (rr >> 4) * 2176 + (rr & 15) * 136;
#pragma unroll
        for (int k2 = 0; k2 < 8; ++k2) {
            int d = lane + 16 * k2;
            float v = (xr[d] - mean) * rstd * s[d] + b[d];
            xr[d] = v;
            xb[d] = f2b(v);
        }
    }
    __syncthreads();
}

// ------- 5-layer transformer: 2 seqs / 256-thr block, weight-register-reuse --------
// R5 verified: 119 us (best). Each wave loads a weight fragment batch ONCE and issues
// 2 MFMAs (one per seq): halves per-CU L2 weight traffic while keeping 4-wave barrier
// granularity. LDS 66560 B -> 2 blocks/CU; grid 512 = one resident round.
// R8 lesson: persistent weight-register prefetch blocks spill at the allocator's
// 128-VGPR operating point (WRITE_SIZE 9.2->19.5 MB) and are net-neutral -> reverted.
__global__ __launch_bounds__(256, 2) void k_tf(const unsigned short* __restrict__ xg,
        const unsigned short* __restrict__ Wb,
        const float* __restrict__ bqkv, const float* __restrict__ bo,
        const float* __restrict__ ln1s, const float* __restrict__ ln1b,
        const float* __restrict__ ln2s, const float* __restrict__ ln2b,
        const float* __restrict__ bff1, const float* __restrict__ bff2,
        float* __restrict__ out) {
    __shared__ __align__(16) float smem[16640];             // 66560 B
    float* xs  = smem;                                      // [32][128] fp32 (2 seqs)
    float* sbB = smem + 4096;                               // [2][16tk][64] scores
    unsigned short* xbB  = (unsigned short*)(smem + 6144);  // [2][16][136] bf16 A-op
    unsigned short* qkvB = (unsigned short*)(smem + 8320);  // [2]: QKV (6528sh) | hid (8320sh)
    const int m0 = blockIdx.x * 2, tid = threadIdx.x;
    const int lane = tid & 63, w = tid >> 6;
    const int mrow = lane & 15, quad = lane >> 4;

    // load + sinusoidal PE (both seqs; xs layout [sid][t][d] contiguous)
    for (int idx = tid; idx < 4096; idx += 256) {
        int sq = idx >> 11, t = (idx >> 7) & 15, d = idx & 127, jj = d >> 1;
        float arg = (float)t * expf(-(float)(2 * jj) * (9.210340371976184f / 128.f));
        float pe = (d & 1) ? cosf(arg) : sinf(arg);
        xs[idx] = bu2f(xg[(size_t)t * (MM * HDIM) + (size_t)(m0 + sq) * HDIM + d]) + pe;
    }
    __syncthreads();
    // initial xs -> xbB (LN epilogues keep it fresh afterwards)
#pragma unroll
    for (int half = 0; half < 2; ++half) {
        int u = tid + half * 256;                // 512 units of 8 elems
        int rr = u >> 4, cc = (u & 15) * 8;
        const float* xp = xs + rr * 128 + cc;
        unsigned v[4];
#pragma unroll
        for (int j = 0; j < 4; ++j)
            v[j] = (unsigned)f2b(xp[2 * j]) | ((unsigned)f2b(xp[2 * j + 1]) << 16);
        *(uint4*)(xbB + (rr >> 4) * 2176 + (rr & 15) * 136 + cc) = make_uint4(v[0], v[1], v[2], v[3]);
    }
    __syncthreads();

    for (int l = 0; l < 5; ++l) {
        const unsigned short* Wl = Wb + (size_t)l * 196608;
        // ---- QKV via MFMA: wave w does nt=6w..6w+5; each wb batch feeds both seqs ----
        {
            bf16x8 af[2][4];
#pragma unroll
            for (int sid = 0; sid < 2; ++sid)
#pragma unroll
                for (int ks = 0; ks < 4; ++ks)
                    af[sid][ks] = *(const bf16x8*)(xbB + sid * 2176 + mrow * 136 + ks * 32 + quad * 8);
#pragma unroll
            for (int ib = 0; ib < 3; ++ib) {
                bf16x8 wb[8];
#pragma unroll
                for (int u = 0; u < 2; ++u) {
                    int nt = w * 6 + ib * 2 + u;
                    const unsigned short* bp = Wl + (size_t)(nt * 4) * 512 + lane * 8;
#pragma unroll
                    for (int ks = 0; ks < 4; ++ks)
                        wb[u * 4 + ks] = *(const bf16x8*)(bp + ks * 512);
                }
                f32x4 acc[2][2];
#pragma unroll
                for (int sid = 0; sid < 2; ++sid)
#pragma unroll
                    for (int u = 0; u < 2; ++u) acc[sid][u] = (f32x4){0.f, 0.f, 0.f, 0.f};
#pragma unroll
                for (int sid = 0; sid < 2; ++sid)
#pragma unroll
                    for (int u = 0; u < 2; ++u)
#pragma unroll
                        for (int ks = 0; ks < 4; ++ks)
                            acc[sid][u] = __builtin_amdgcn_mfma_f32_16x16x32_bf16(af[sid][ks], wb[u * 4 + ks], acc[sid][u], 0, 0, 0);
#pragma unroll
                for (int sid = 0; sid < 2; ++sid)
#pragma unroll
                    for (int u = 0; u < 2; ++u) {
                        int nt = w * 6 + ib * 2 + u, mt = nt >> 3, cc = nt & 7;
                        int col = cc * 16 + mrow;
                        float bb = bqkv[l * 384 + mt * 128 + col];
                        unsigned short* dst = qkvB + sid * 6528 + mt * 2176;   // Q/K/V of sid
#pragma unroll
                        for (int r = 0; r < 4; ++r)
                            dst[(quad * 4 + r) * 136 + col] = f2b(acc[sid][u][r] + bb);
                    }
            }
        }
        __syncthreads();
        // ---- scores (fp32 VALU, bf16 Q/K): thread = (hh, tq, tk0..tk0+3) x 2 seqs ----
        {
            int hh = tid >> 6, tq = (tid >> 2) & 15, tk0 = (tid & 3) * 4;
#pragma unroll
            for (int sid = 0; sid < 2; ++sid) {
                const unsigned short* qp = qkvB + sid * 6528 + tq * 136 + hh * 32;
                const unsigned short* kb = qkvB + sid * 6528 + 2176;
                float a[4] = {0.f, 0.f, 0.f, 0.f};
#pragma unroll
                for (int d4 = 0; d4 < 4; ++d4) {
                    uint4 qv = *(const uint4*)(qp + d4 * 8);
                    float qf[8];
                    qf[0] = bu2f((unsigned short)(qv.x & 0xffff)); qf[1] = bu2f((unsigned short)(qv.x >> 16));
                    qf[2] = bu2f((unsigned short)(qv.y & 0xffff)); qf[3] = bu2f((unsigned short)(qv.y >> 16));
                    qf[4] = bu2f((unsigned short)(qv.z & 0xffff)); qf[5] = bu2f((unsigned short)(qv.z >> 16));
                    qf[6] = bu2f((unsigned short)(qv.w & 0xffff)); qf[7] = bu2f((unsigned short)(qv.w >> 16));
#pragma unroll
                    for (int j = 0; j < 4; ++j) {
                        uint4 kv = *(const uint4*)(kb + (tk0 + j) * 136 + hh * 32 + d4 * 8);
                        a[j] += qf[0] * bu2f((unsigned short)(kv.x & 0xffff));
                        a[j] += qf[1] * bu2f((unsigned short)(kv.x >> 16));
                        a[j] += qf[2] * bu2f((unsigned short)(kv.y & 0xffff));
                        a[j] += qf[3] * bu2f((unsigned short)(kv.y >> 16));
                        a[j] += qf[4] * bu2f((unsigned short)(kv.z & 0xffff));
                        a[j] += qf[5] * bu2f((unsigned short)(kv.z >> 16));
                        a[j] += qf[6] * bu2f((unsigned short)(kv.w & 0xffff));
                        a[j] += qf[7] * bu2f((unsigned short)(kv.w >> 16));
                    }
                }
#pragma unroll
                for (int j = 0; j < 4; ++j)
                    sbB[sid * 1024 + (tk0 + j) * 64 + hh * 16 + tq] = a[j] * 0.17677669529663687f;
            }
        }
        __syncthreads();
        if (tid < 128) {   // softmax per (seq, hh, tq) column
            float* sbp = sbB + (tid >> 6) * 1024;
            int cc = tid & 63;
            float mx = -1e30f;
#pragma unroll
            for (int u = 0; u < 16; ++u) mx = fmaxf(mx, sbp[u * 64 + cc]);
            float s = 0.f;
#pragma unroll
            for (int u = 0; u < 16; ++u) { float e = __expf(sbp[u * 64 + cc] - mx); sbp[u * 64 + cc] = e; s += e; }
            float inv = 1.f / s;
#pragma unroll
            for (int u = 0; u < 16; ++u) sbp[u * 64 + cc] *= inv;
        }
        __syncthreads();
        // ---- O = P @ V (fp32, bf16 V) -> xbB, both seqs ----
        {
            int o = tid & 127, r0p = (tid >> 7) * 8, hh = o >> 5;
#pragma unroll
            for (int sid = 0; sid < 2; ++sid) {
                const unsigned short* vb = qkvB + sid * 6528 + 4352;
                const float* sb = sbB + sid * 1024;
                float accp[8] = {0, 0, 0, 0, 0, 0, 0, 0};
                for (int u = 0; u < 16; ++u) {
                    float vv = bu2f(vb[u * 136 + o]);
                    const float* pp = sb + u * 64 + hh * 16 + r0p;
#pragma unroll
                    for (int r = 0; r < 8; ++r) accp[r] += pp[r] * vv;
                }
#pragma unroll
                for (int r = 0; r < 8; ++r)
                    xbB[sid * 2176 + (r0p + r) * 136 + o] = f2b(accp[r]);
            }
        }
        __syncthreads();
        // ---- Wo via MFMA: wave w does nt = 2w, 2w+1; wb batch feeds both seqs ----
        {
            bf16x8 af[2][4];
#pragma unroll
            for (int sid = 0; sid < 2; ++sid)
#pragma unroll
                for (int ks = 0; ks < 4; ++ks)
                    af[sid][ks] = *(const bf16x8*)(xbB + sid * 2176 + mrow * 136 + ks * 32 + quad * 8);
            const unsigned short* Ws = Wl + 49152;
            bf16x8 wb[8];
#pragma unroll
            for (int u = 0; u < 2; ++u) {
                int nt = w * 2 + u;
#pragma unroll
                for (int ks = 0; ks < 4; ++ks)
                    wb[u * 4 + ks] = *(const bf16x8*)(Ws + (size_t)((nt * 4 + ks) * 64 + lane) * 8);
            }
            f32x4 acc[2][2];
#pragma unroll
            for (int sid = 0; sid < 2; ++sid)
#pragma unroll
                for (int u = 0; u < 2; ++u) acc[sid][u] = (f32x4){0.f, 0.f, 0.f, 0.f};
#pragma unroll
            for (int sid = 0; sid < 2; ++sid)
#pragma unroll
                for (int u = 0; u < 2; ++u)
#pragma unroll
                    for (int ks = 0; ks < 4; ++ks)
                        acc[sid][u] = __builtin_amdgcn_mfma_f32_16x16x32_bf16(af[sid][ks], wb[u * 4 + ks], acc[sid][u], 0, 0, 0);
#pragma unroll
            for (int sid = 0; sid < 2; ++sid)
#pragma unroll
                for (int u = 0; u < 2; ++u) {
                    int col = (w * 2 + u) * 16 + mrow;
                    float bb = bo[l * 128 + col];
#pragma unroll
                    for (int r = 0; r < 4; ++r)
                        xs[sid * 2048 + (quad * 4 + r) * 128 + col] += acc[sid][u][r] + bb;
                }
        }
        __syncthreads();
        ln2x(xs, xbB, ln1s + l * 128, ln1b + l * 128);     // also refreshes xbB
        // ---- FF1 via MFMA: wave w does nt = 8w..8w+7; wb batch feeds both seqs ----
        {
            bf16x8 af[2][4];
#pragma unroll
            for (int sid = 0; sid < 2; ++sid)
#pragma unroll
                for (int ks = 0; ks < 4; ++ks)
                    af[sid][ks] = *(const bf16x8*)(xbB + sid * 2176 + mrow * 136 + ks * 32 + quad * 8);
            const unsigned short* Ws = Wl + 65536;
#pragma unroll
            for (int ib = 0; ib < 4; ++ib) {
                bf16x8 wb[8];
#pragma unroll
                for (int u = 0; u < 2; ++u) {
                    int nt = w * 8 + ib * 2 + u;
#pragma unroll
                    for (int ks = 0; ks < 4; ++ks)
                        wb[u * 4 + ks] = *(const bf16x8*)(Ws + (size_t)((nt * 4 + ks) * 64 + lane) * 8);
                }
                f32x4 acc[2][2];
#pragma unroll
                for (int sid = 0; sid < 2; ++sid)
#pragma unroll
                    for (int u = 0; u < 2; ++u) acc[sid][u] = (f32x4){0.f, 0.f, 0.f, 0.f};
#pragma unroll
                for (int sid = 0; sid < 2; ++sid)
#pragma unroll
                    for (int u = 0; u < 2; ++u)
#pragma unroll
                        for (int ks = 0; ks < 4; ++ks)
                            acc[sid][u] = __builtin_amdgcn_mfma_f32_16x16x32_bf16(af[sid][ks], wb[u * 4 + ks], acc[sid][u], 0, 0, 0);
#pragma unroll
                for (int sid = 0; sid < 2; ++sid)
#pragma unroll
                    for (int u = 0; u < 2; ++u) {
                        int col = (w * 8 + ib * 2 + u) * 16 + mrow;
                        float bb = bff1[l * 512 + col];
                        unsigned short* hid16 = qkvB + sid * 8320;
#pragma unroll
                        for (int r = 0; r < 4; ++r) {
                            float v = fmaxf(acc[sid][u][r] + bb, 0.f);
                            hid16[(quad * 4 + r) * 520 + col] = f2b(v);
                        }
                    }
            }
        }
        __syncthreads();
        // ---- FF2 via MFMA: 2 nt x 16 ks per wave; w0/w1 batches feed both seqs ----
        {
            f32x4 a[2][2];
#pragma unroll
            for (int sid = 0; sid < 2; ++sid)
#pragma unroll
                for (int u = 0; u < 2; ++u) a[sid][u] = (f32x4){0.f, 0.f, 0.f, 0.f};
            const unsigned short* Ws = Wl + 131072;
            int nt0 = w * 2, nt1 = w * 2 + 1;
#pragma unroll
            for (int kb = 0; kb < 4; ++kb) {
                bf16x8 w0[4], w1[4];
#pragma unroll
                for (int kk = 0; kk < 4; ++kk) {
                    int ks = kb * 4 + kk;
                    w0[kk] = *(const bf16x8*)(Ws + (size_t)((nt0 * 16 + ks) * 64 + lane) * 8);
                    w1[kk] = *(const bf16x8*)(Ws + (size_t)((nt1 * 16 + ks) * 64 + lane) * 8);
                }
#pragma unroll
                for (int sid = 0; sid < 2; ++sid) {
                    const unsigned short* hid16 = qkvB + sid * 8320;
#pragma unroll
                    for (int kk = 0; kk < 4; ++kk) {
                        int ks = kb * 4 + kk;
                        bf16x8 afb = *(const bf16x8*)(hid16 + mrow * 520 + ks * 32 + quad * 8);
                        a[sid][0] = __builtin_amdgcn_mfma_f32_16x16x32_bf16(afb, w0[kk], a[sid][0], 0, 0, 0);
                        a[sid][1] = __builtin_amdgcn_mfma_f32_16x16x32_bf16(afb, w1[kk], a[sid][1], 0, 0, 0);
                    }
                }
            }
            int col0 = nt0 * 16 + mrow, col1 = nt1 * 16 + mrow;
            float bb0 = bff2[l * 128 + col0], bb1 = bff2[l * 128 + col1];
#pragma unroll
            for (int sid = 0; sid < 2; ++sid)
#pragma unroll
                for (int r = 0; r < 4; ++r) {
                    xs[sid * 2048 + (quad * 4 + r) * 128 + col0] += a[sid][0][r] + bb0;
                    xs[sid * 2048 + (quad * 4 + r) * 128 + col1] += a[sid][1][r] + bb1;
                }
        }
        __syncthreads();
        ln2x(xs, xbB, ln2s + l * 128, ln2b + l * 128);     // xbB ready for next layer
    }
    for (int idx = tid; idx < 4096; idx += 256)
        out[(size_t)m0 * 2048 + idx] = xs[idx];
}

extern "C" void kernel_launch(void* const* d_in, const int* in_sizes, int n_in,
                              void* d_out, int out_size, void* d_ws, size_t ws_size,
                              hipStream_t stream) {
    (void)in_sizes; (void)n_in; (void)out_size; (void)ws_size;
    const int*   ego  = (const int*)d_in[0];
    const float* pos  = (const float*)d_in[1];
    const float* adj  = (const float*)d_in[2];
    const float* g1W  = (const float*)d_in[3];
    const float* g1as = (const float*)d_in[4];
    const float* g1ad = (const float*)d_in[5];
    const float* g1b  = (const float*)d_in[6];
    const float* gW   = (const float*)d_in[7];
    const float* gas  = (const float*)d_in[8];
    const float* gad  = (const float*)d_in[9];
    const float* gb   = (const float*)d_in[10];
    const float* Wqkv = (const float*)d_in[11];
    const float* bqkv = (const float*)d_in[12];
    const float* Wo   = (const float*)d_in[13];
    const float* bo   = (const float*)d_in[14];
    const float* l1s  = (const float*)d_in[15];
    const float* l1b  = (const float*)d_in[16];
    const float* l2s  = (const float*)d_in[17];
    const float* l2b  = (const float*)d_in[18];
    const float* Wff1 = (const float*)d_in[19];
    const float* bff1 = (const float*)d_in[20];
    const float* Wff2 = (const float*)d_in[21];
    const float* bff2 = (const float*)d_in[22];

    unsigned short* x0  = (unsigned short*)d_ws;       // 2,097,152 sh (4 MB)
    unsigned short* x1  = x0 + 2097152;                // 4 MB
    unsigned short* h16 = x1 + 2097152;                // 8,388,608 sh (16 MB)
    float* ssb = (float*)(h16 + 8388608);              // 65,536 f
    float* sdb = ssb + 65536;                          // 65,536 f
    float* mfl = sdb + 65536;                          // 16,384 f
    int*   cnt = (int*)(mfl + 16384);                  // 16,384 i
    int*   nbr = cnt + 16384;                          // 1,048,576 i
    unsigned short* Wb16 = (unsigned short*)(nbr + 1048576);  // 1,310,720 sh (~2.6 MB)
    unsigned short* Wg16 = Wb16 + 983040;              // GAT weight frags

    k_prep<<<640, 256, 0, stream>>>(Wqkv, Wo, Wff1, Wff2, gW, Wb16);
    k_init<<<64, 256, 0, stream>>>(ego, mfl, cnt);
    k_edges<<<1024, 256, 0, stream>>>(adj, mfl, cnt, nbr);

    // GAT layer 1 (F=2), projection + ss/sd fused
    k_gat1<<<NROWS, 128, 0, stream>>>(pos, g1W, g1as, g1ad, h16, ssb, sdb);
    k_agg<<<4096, 256, 0, stream>>>(h16, ssb, sdb, cnt, nbr, mfl, g1b, x0);

    unsigned short* xin = x0; unsigned short* xout = x1;
    for (int L = 0; L < 5; ++L) {
        k_gat_h<<<512, 256, 0, stream>>>(xin, Wg16 + (size_t)L * 65536,
                                         gas + L * 512, gad + L * 512, h16, ssb, sdb);
        k_agg<<<4096, 256, 0, stream>>>(h16, ssb, sdb, cnt, nbr, mfl, gb + L * 128, xout);
        unsigned short* tmp = xin; xin = xout; xout = tmp;
    }

    k_tf<<<512, 256, 0, stream>>>(xin, Wb16, bqkv, bo, l1s, l1b, l2s, l2b,
                                  bff1, bff2, (float*)d_out);
}